// Round 9
// baseline (513.541 us; speedup 1.0000x reference)
//
#include <hip/hip_runtime.h>
#include <hip/hip_bf16.h>
#include <math.h>

#define SLOPE 0.2f

typedef __attribute__((ext_vector_type(8))) short bf16x8;
typedef __attribute__((ext_vector_type(4))) float f32x4;

// bf16 helpers (manual, RNE)
__device__ inline unsigned short f2bf(float f) {
    unsigned u = __float_as_uint(f);
    u += 0x7FFF + ((u >> 16) & 1);
    return (unsigned short)(u >> 16);
}
__device__ inline float bf2f(unsigned short s) {
    return __uint_as_float(((unsigned)s) << 16);
}

// ---------------- CSR build ----------------

__global__ void deg_kernel(const int* __restrict__ dst, int* __restrict__ deg, int E) {
    int i = blockIdx.x * blockDim.x + threadIdx.x;
    if (i < E) atomicAdd(&deg[dst[i]], 1);
}

__global__ __launch_bounds__(1024) void scan_kernel(const int* __restrict__ deg,
                                                    int* __restrict__ offs, int n) {
    __shared__ int sums[1024];
    int t = threadIdx.x;
    int chunk = (n + 1023) >> 10;
    int beg = t * chunk;
    int end = beg + chunk; if (end > n) end = n;
    int s = 0;
    for (int i = beg; i < end && i >= 0; ++i) s += deg[i];
    sums[t] = s;
    __syncthreads();
    for (int off = 1; off < 1024; off <<= 1) {
        int v = (t >= off) ? sums[t - off] : 0;
        __syncthreads();
        sums[t] += v;
        __syncthreads();
    }
    int run = (t == 0) ? 0 : sums[t - 1];
    for (int i = beg; i < end; ++i) { offs[i] = run; run += deg[i]; }
    if (t == 1023) offs[n] = run;   // == E
}

__global__ void fill_kernel(const int* __restrict__ src, const int* __restrict__ dst,
                            const int* __restrict__ offs, int* __restrict__ cursor,
                            int* __restrict__ csr_src, int E) {
    int i = blockIdx.x * blockDim.x + threadIdx.x;
    if (i < E) {
        int d = dst[i];
        int p = atomicAdd(&cursor[d], 1);
        csr_src[offs[d] + p] = src[i];
    }
}

// ---------------- conversion kernels ----------------

__global__ void cvt_x_kernel(const float4* __restrict__ X4, ushort4* __restrict__ O4,
                             int n4) {
    int i = blockIdx.x * blockDim.x + threadIdx.x;
    if (i < n4) {
        const float4 v = X4[i];
        ushort4 o;
        o.x = f2bf(v.x); o.y = f2bf(v.y); o.z = f2bf(v.z); o.w = f2bf(v.w);
        O4[i] = o;
    }
}

// Wt[c][k] = bf16(W[k][c]); K=256, M=256. grid 256 (k), block 256 (c).
__global__ void cvt_wt_kernel(const float* __restrict__ W, unsigned short* __restrict__ Wt) {
    const int k = blockIdx.x, c = threadIdx.x;
    Wt[c * 256 + k] = f2bf(W[k * 256 + c]);
}

// ---------------- layer-1 GEMM via bf16 MFMA (no LDS, no barriers) ------------
// D[m=feature][n=node] = Wt-frag (A) x Xbf-frag (B), 16x16x32 tiles.
// Wave owns 16 nodes x 256 features: 16 m-tiles, 8 k-chunks, acc = 16 x f32x4.
// A-frag: lane reads Wt[m0+(lane&15)][k0+quad*8 ..+8]  (16B global, L2-hot)
// B-frag: lane reads Xbf[node(lane&15)][k0+quad*8 ..+8] (16B global)
// D-frag: col=lane&15 -> node, row=quad*4+reg -> feature  [m89-verified]
__global__ __launch_bounds__(256) void gemm1_mfma(const unsigned short* __restrict__ Xbf,
                                                  const unsigned short* __restrict__ Wt,
                                                  const float* __restrict__ AL,
                                                  const float* __restrict__ AR,
                                                  unsigned short* __restrict__ Hout,
                                                  float* __restrict__ el,
                                                  float* __restrict__ er, int n) {
    const int tid = threadIdx.x;
    const int wave = tid >> 6, lane = tid & 63;
    const int col16 = lane & 15, quad = lane >> 4;
    const int node = blockIdx.x * 64 + wave * 16 + col16;
    const int nodec = (node < n) ? node : (n - 1);

    f32x4 acc[16];
#pragma unroll
    for (int t = 0; t < 16; ++t) acc[t] = (f32x4){0.f, 0.f, 0.f, 0.f};

    const unsigned short* xrow = Xbf + (long long)nodec * 256;
    for (int ch = 0; ch < 8; ++ch) {
        const bf16x8 bfrag = *(const bf16x8*)(xrow + ch * 32 + quad * 8);
#pragma unroll
        for (int t = 0; t < 16; ++t) {
            const bf16x8 afrag =
                *(const bf16x8*)(Wt + (t * 16 + col16) * 256 + ch * 32 + quad * 8);
            acc[t] = __builtin_amdgcn_mfma_f32_16x16x32_bf16(afrag, bfrag, acc[t], 0, 0, 0);
        }
    }

    // epilogue: store h1 bf16 + el/er dot products
    float elp[4] = {0.f, 0.f, 0.f, 0.f}, erp[4] = {0.f, 0.f, 0.f, 0.f};
#pragma unroll
    for (int t = 0; t < 16; ++t) {
        const int m0 = t * 16;
        const int head = m0 >> 6;
        if (node < n) {
            ushort4 pk;
            pk.x = f2bf(acc[t][0]); pk.y = f2bf(acc[t][1]);
            pk.z = f2bf(acc[t][2]); pk.w = f2bf(acc[t][3]);
            *(ushort4*)&Hout[(long long)node * 256 + m0 + quad * 4] = pk;
        }
#pragma unroll
        for (int r = 0; r < 4; ++r) {
            const int d = (m0 & 63) + quad * 4 + r;
            elp[head] = fmaf(acc[t][r], AL[head * 64 + d], elp[head]);
            erp[head] = fmaf(acc[t][r], AR[head * 64 + d], erp[head]);
        }
    }
#pragma unroll
    for (int h = 0; h < 4; ++h) {
        elp[h] += __shfl_xor(elp[h], 16, 64); elp[h] += __shfl_xor(elp[h], 32, 64);
        erp[h] += __shfl_xor(erp[h], 16, 64); erp[h] += __shfl_xor(erp[h], 32, 64);
    }
    if (quad == 0 && node < n) {
        *(float4*)&el[(long long)node * 4] = make_float4(elp[0], elp[1], elp[2], elp[3]);
        *(float4*)&er[(long long)node * 4] = make_float4(erp[0], erp[1], erp[2], erp[3]);
    }
}

// ---------------- fp32 register-tiled GEMM (layer 2) ----------------
template <int K, int M, int BN, int H, typename OT>
__global__ __launch_bounds__(256) void gemm_tile(const float* __restrict__ X,
                                                 const float* __restrict__ W,
                                                 const float* __restrict__ AL,
                                                 const float* __restrict__ AR,
                                                 OT* __restrict__ Hout,
                                                 float* __restrict__ el,
                                                 float* __restrict__ er, int n) {
    constexpr int BM = 64;
    constexpr int BK = 16;
    constexpr int BMP = BM + 4;
    constexpr int CT = BN / 16;
    constexpr int NHB = BN / 64;
    constexpr int WPH = 4 / NHB;
    __shared__ __align__(16) float As[BK * BMP];
    __shared__ __align__(16) float Bs[BK * BN];
    __shared__ float elp[4][BM];
    __shared__ float erp[4][BM];

    const int tid = threadIdx.x;
    const int tx = tid & 15;
    const int ty = tid >> 4;
    const int wave = tid >> 6;
    const int lane = tid & 63;
    const int row0 = blockIdx.x * BM;
    const int cb = blockIdx.y;

    float acc[4][CT];
#pragma unroll
    for (int i = 0; i < 4; ++i)
#pragma unroll
        for (int j = 0; j < CT; ++j) acc[i][j] = 0.f;

    const float4* X4 = (const float4*)X;
    const float4* W4 = (const float4*)W;

    for (int k0 = 0; k0 < K; k0 += BK) {
        {
            const int r = tid >> 2, c4 = tid & 3;
            const int row = row0 + r;
            float4 v = make_float4(0.f, 0.f, 0.f, 0.f);
            if (row < n) v = X4[(long long)row * (K / 4) + (k0 >> 2) + c4];
            As[(c4 * 4 + 0) * BMP + r] = v.x;
            As[(c4 * 4 + 1) * BMP + r] = v.y;
            As[(c4 * 4 + 2) * BMP + r] = v.z;
            As[(c4 * 4 + 3) * BMP + r] = v.w;
        }
        constexpr int BF4 = 4 * BN;
#pragma unroll
        for (int p = tid; p < BF4; p += 256) {
            const int r = p / (BN / 4), c4 = p % (BN / 4);
            ((float4*)Bs)[(r * BN + c4 * 4) >> 2] =
                W4[(((long long)(k0 + r)) * M + cb * BN + c4 * 4) >> 2];
        }
        __syncthreads();

#pragma unroll
        for (int kk = 0; kk < BK; ++kk) {
            const float4 av = *(const float4*)&As[kk * BMP + tx * 4];
            float bv[CT];
#pragma unroll
            for (int q = 0; q < CT / 4; ++q) {
                const float4 b = *(const float4*)&Bs[kk * BN + ty * CT + q * 4];
                bv[q * 4 + 0] = b.x; bv[q * 4 + 1] = b.y;
                bv[q * 4 + 2] = b.z; bv[q * 4 + 3] = b.w;
            }
            const float arow[4] = {av.x, av.y, av.z, av.w};
#pragma unroll
            for (int i = 0; i < 4; ++i)
#pragma unroll
                for (int j = 0; j < CT; ++j)
                    acc[i][j] = fmaf(arow[i], bv[j], acc[i][j]);
        }
        __syncthreads();
    }

    const int hq = ty / (16 / NHB);
    const int head = cb * NHB + hq;
    const int d0 = (ty % (16 / NHB)) * CT;
    float alw[CT], arw[CT];
#pragma unroll
    for (int j = 0; j < CT; ++j) {
        alw[j] = AL[head * 64 + d0 + j];
        arw[j] = AR[head * 64 + d0 + j];
    }

#pragma unroll
    for (int i = 0; i < 4; ++i) {
        const int row = row0 + tx * 4 + i;
        if (row < n) {
            const long long base = (long long)row * M + cb * BN + ty * CT;
            if (sizeof(OT) == 2) {
#pragma unroll
                for (int q = 0; q < CT / 4; ++q) {
                    ushort4 pk;
                    pk.x = f2bf(acc[i][q * 4 + 0]);
                    pk.y = f2bf(acc[i][q * 4 + 1]);
                    pk.z = f2bf(acc[i][q * 4 + 2]);
                    pk.w = f2bf(acc[i][q * 4 + 3]);
                    *(ushort4*)&((unsigned short*)Hout)[base + q * 4] = pk;
                }
            } else {
#pragma unroll
                for (int q = 0; q < CT / 4; ++q)
                    *(float4*)&((float*)Hout)[base + q * 4] =
                        make_float4(acc[i][q * 4], acc[i][q * 4 + 1],
                                    acc[i][q * 4 + 2], acc[i][q * 4 + 3]);
            }
        }
        float a = 0.f, b = 0.f;
#pragma unroll
        for (int j = 0; j < CT; ++j) {
            a = fmaf(acc[i][j], alw[j], a);
            b = fmaf(acc[i][j], arw[j], b);
        }
        a += __shfl_xor(a, 16, 64); a += __shfl_xor(a, 32, 64);
        b += __shfl_xor(b, 16, 64); b += __shfl_xor(b, 32, 64);
        if (lane < 16) {
            elp[wave][tx * 4 + i] = a;
            erp[wave][tx * 4 + i] = b;
        }
    }
    __syncthreads();
    for (int t = tid; t < BM * NHB; t += 256) {
        const int rl = t & 63, hb = t >> 6;
        const int row = row0 + rl;
        if (row < n) {
            float s = 0.f, s2 = 0.f;
#pragma unroll
            for (int w = 0; w < WPH; ++w) {
                s += elp[hb * WPH + w][rl];
                s2 += erp[hb * WPH + w][rl];
            }
            el[row * H + cb * NHB + hb] = s;
            er[row * H + cb * NHB + hb] = s2;
        }
    }
}

// ---------------- softmax gather-aggregate (no online-max) ----------------
template <int H, int D, int VEC, bool ELU, typename HT>
__global__ __launch_bounds__(256) void aggr_kernel(const HT* __restrict__ Hf,
                                                   const float* __restrict__ el,
                                                   const float* __restrict__ er,
                                                   const int* __restrict__ offs,
                                                   const int* __restrict__ csr_src,
                                                   const float* __restrict__ bias,
                                                   float* __restrict__ out, int n) {
    const int node = (blockIdx.x * blockDim.x + threadIdx.x) >> 6;
    const int lane = threadIdx.x & 63;
    if (node >= n) return;
    const int head = (lane * VEC) / D;
    const float erv = er[node * H + head];
    const int beg = offs[node], end = offs[node + 1];
    float l = 0.f;
    float acc[VEC];
#pragma unroll
    for (int j = 0; j < VEC; ++j) acc[j] = 0.f;
#pragma unroll 2
    for (int i = beg; i < end; ++i) {
        const int s = csr_src[i];
        float e = el[s * H + head] + erv;
        e = (e > 0.f) ? e : SLOPE * e;
        e = fminf(e, 80.f);
        const float p = __expf(e);
        const HT* hp = Hf + (long long)s * (H * D) + lane * VEC;
        float hv[VEC];
        if (sizeof(HT) == 2) {
            if (VEC == 4) {
                const ushort4 u = *(const ushort4*)hp;
                hv[0] = bf2f(u.x);
                if (VEC > 1) { hv[1] = bf2f(u.y); hv[2] = bf2f(u.z); hv[3] = bf2f(u.w); }
            } else {
                hv[0] = bf2f(*(const unsigned short*)hp);
            }
        } else {
            if (VEC == 4) {
                const float4 f = *(const float4*)hp;
                hv[0] = f.x;
                if (VEC > 1) { hv[1] = f.y; hv[2] = f.z; hv[3] = f.w; }
            } else {
                hv[0] = *(const float*)hp;
            }
        }
        l += p;
#pragma unroll
        for (int j = 0; j < VEC; ++j) acc[j] = fmaf(p, hv[j], acc[j]);
    }
    const float inv = (l > 0.f) ? 1.f / l : 0.f;
    float v[VEC];
#pragma unroll
    for (int j = 0; j < VEC; ++j) {
        v[j] = acc[j] * inv + bias[lane * VEC + j];
        if (ELU) v[j] = (v[j] > 0.f) ? v[j] : expm1f(v[j]);
    }
    float* op = out + (long long)node * (H * D) + lane * VEC;
    if (VEC == 4) {
        *(float4*)op = make_float4(v[0], v[1], v[2], v[3]);
    } else {
        *op = v[0];
    }
}

// ---------------- launch ----------------

extern "C" void kernel_launch(void* const* d_in, const int* in_sizes, int n_in,
                              void* d_out, int out_size, void* d_ws, size_t ws_size,
                              hipStream_t stream) {
    const float* feat = (const float*)d_in[0];
    const int*   src  = (const int*)d_in[1];
    const int*   dst  = (const int*)d_in[2];
    const float* W1   = (const float*)d_in[3];
    const float* al1  = (const float*)d_in[4];
    const float* ar1  = (const float*)d_in[5];
    const float* b1   = (const float*)d_in[6];
    const float* W2   = (const float*)d_in[7];
    const float* al2  = (const float*)d_in[8];
    const float* ar2  = (const float*)d_in[9];
    const float* b2   = (const float*)d_in[10];
    float* out = (float*)d_out;

    const int IN = 256, HID = 64, OUT = 64, H1 = 4, H2 = 1;
    const int N = in_sizes[0] / IN;   // 50000
    const int E = in_sizes[1];        // 800000

    size_t off = 0;
    auto alloc = [&](size_t bytes) {
        void* p = (char*)d_ws + off;
        off += (bytes + 255) & ~(size_t)255;
        return p;
    };
    int*   deg    = (int*)alloc((size_t)N * 4);
    int*   cursor = (int*)alloc((size_t)N * 4);
    int*   offs   = (int*)alloc((size_t)(N + 1) * 4);
    int*   csr    = (int*)alloc((size_t)E * 4);
    unsigned short* h1  = (unsigned short*)alloc((size_t)N * H1 * HID * 2);  // bf16
    unsigned short* xbf = (unsigned short*)alloc((size_t)N * IN * 2);        // bf16 X
    unsigned short* wt  = (unsigned short*)alloc((size_t)IN * H1 * HID * 2); // bf16 W1^T
    float* el1    = (float*)alloc((size_t)N * H1 * 4);
    float* er1    = (float*)alloc((size_t)N * H1 * 4);
    float* x2     = (float*)alloc((size_t)N * H1 * HID * 4);
    float* h2     = (float*)alloc((size_t)N * H2 * OUT * 4);
    float* el2    = (float*)alloc((size_t)N * H2 * 4);
    float* er2    = (float*)alloc((size_t)N * H2 * 4);
    (void)ws_size;

    hipMemsetAsync(deg, 0, (size_t)N * 4, stream);
    hipMemsetAsync(cursor, 0, (size_t)N * 4, stream);

    deg_kernel<<<(E + 255) / 256, 256, 0, stream>>>(dst, deg, E);
    scan_kernel<<<1, 1024, 0, stream>>>(deg, offs, N);
    fill_kernel<<<(E + 255) / 256, 256, 0, stream>>>(src, dst, offs, cursor, csr, E);

    // bf16 conversions for layer-1 MFMA
    {
        const int n4 = N * IN / 4;
        cvt_x_kernel<<<(n4 + 255) / 256, 256, 0, stream>>>((const float4*)feat,
                                                           (ushort4*)xbf, n4);
        cvt_wt_kernel<<<256, 256, 0, stream>>>(W1, wt);
    }

    // ---- layer 1 ----  (MFMA, 64 nodes/block, no LDS/barriers)
    gemm1_mfma<<<(N + 63) / 64, 256, 0, stream>>>(xbf, wt, al1, ar1, h1, el1, er1, N);
    aggr_kernel<4, 64, 4, true, unsigned short>
        <<<(N + 3) / 4, 256, 0, stream>>>(h1, el1, er1, offs, csr, b1, x2, N);
    // ---- layer 2 ----  (fp32 vector, BM=64, BN=64)
    {
        dim3 g((N + 63) / 64, 1);
        gemm_tile<256, 64, 64, 1, float>
            <<<g, 256, 0, stream>>>(x2, W2, al2, ar2, h2, el2, er2, N);
    }
    aggr_kernel<1, 64, 1, false, float>
        <<<(N + 3) / 4, 256, 0, stream>>>(h2, el2, er2, offs, csr, b2, out, N);
}

// Round 10
// 466.466 us; speedup vs baseline: 1.1009x; 1.1009x over previous
//
#include <hip/hip_runtime.h>
#include <hip/hip_bf16.h>
#include <math.h>

#define SLOPE 0.2f

typedef __attribute__((ext_vector_type(8))) short bf16x8;
typedef __attribute__((ext_vector_type(4))) float f32x4;

// bf16 helpers (manual, RNE)
__device__ inline unsigned short f2bf(float f) {
    unsigned u = __float_as_uint(f);
    u += 0x7FFF + ((u >> 16) & 1);
    return (unsigned short)(u >> 16);
}
__device__ inline float bf2f(unsigned short s) {
    return __uint_as_float(((unsigned)s) << 16);
}

// ---------------- CSR build ----------------

__global__ void deg_kernel(const int* __restrict__ dst, int* __restrict__ deg, int E) {
    int i = blockIdx.x * blockDim.x + threadIdx.x;
    if (i < E) atomicAdd(&deg[dst[i]], 1);
}

__global__ __launch_bounds__(1024) void scan_kernel(const int* __restrict__ deg,
                                                    int* __restrict__ offs, int n) {
    __shared__ int sums[1024];
    int t = threadIdx.x;
    int chunk = (n + 1023) >> 10;
    int beg = t * chunk;
    int end = beg + chunk; if (end > n) end = n;
    int s = 0;
    for (int i = beg; i < end && i >= 0; ++i) s += deg[i];
    sums[t] = s;
    __syncthreads();
    for (int off = 1; off < 1024; off <<= 1) {
        int v = (t >= off) ? sums[t - off] : 0;
        __syncthreads();
        sums[t] += v;
        __syncthreads();
    }
    int run = (t == 0) ? 0 : sums[t - 1];
    for (int i = beg; i < end; ++i) { offs[i] = run; run += deg[i]; }
    if (t == 1023) offs[n] = run;   // == E
}

__global__ void fill_kernel(const int* __restrict__ src, const int* __restrict__ dst,
                            const int* __restrict__ offs, int* __restrict__ cursor,
                            int* __restrict__ csr_src, int E) {
    int i = blockIdx.x * blockDim.x + threadIdx.x;
    if (i < E) {
        int d = dst[i];
        int p = atomicAdd(&cursor[d], 1);
        csr_src[offs[d] + p] = src[i];
    }
}

// ---------------- conversion kernels ----------------

__global__ void cvt_x_kernel(const float4* __restrict__ X4, ushort4* __restrict__ O4,
                             int n4) {
    int i = blockIdx.x * blockDim.x + threadIdx.x;
    if (i < n4) {
        const float4 v = X4[i];
        ushort4 o;
        o.x = f2bf(v.x); o.y = f2bf(v.y); o.z = f2bf(v.z); o.w = f2bf(v.w);
        O4[i] = o;
    }
}

// Wt[c][k] = bf16(W[k][c]); K=256, M=256. grid 256 (k), block 256 (c).
__global__ void cvt_wt_kernel(const float* __restrict__ W, unsigned short* __restrict__ Wt) {
    const int k = blockIdx.x, c = threadIdx.x;
    Wt[c * 256 + k] = f2bf(W[k * 256 + c]);
}

// ---------------- layer-1 GEMM: LDS-tiled bf16 MFMA ----------------
// Block: 128 nodes x 128 feats (fb selects feature half), K=256 in 64-chunks.
// LDS rows padded to 72 ushorts (144 B) -> 2-way bank aliasing (free).
// Wave w owns nodes [w*32, w*32+32) (2 n-tiles) x all 8 feat-tiles.
// Frag layouts identical to R9's verified kernel (A[m=col16][k=quad*8+j],
// B[n=col16][k=quad*8+j], D: col16->node, quad*4+reg->feat).
__global__ __launch_bounds__(256) void gemm1_mfma(const unsigned short* __restrict__ Xbf,
                                                  const unsigned short* __restrict__ Wt,
                                                  const float* __restrict__ AL,
                                                  const float* __restrict__ AR,
                                                  unsigned short* __restrict__ Hout,
                                                  float* __restrict__ el,
                                                  float* __restrict__ er, int n) {
    constexpr int LDR = 72;                 // LDS row stride (64 data + 8 pad)
    __shared__ __align__(16) unsigned short Xs[128 * LDR];
    __shared__ __align__(16) unsigned short Ws[128 * LDR];

    const int tid = threadIdx.x;
    const int wave = tid >> 6, lane = tid & 63;
    const int col16 = lane & 15, quad = lane >> 4;
    const int node0 = blockIdx.x * 128;
    const int fb = blockIdx.y;              // feature half

    f32x4 acc[8][2];
#pragma unroll
    for (int ft = 0; ft < 8; ++ft)
#pragma unroll
        for (int nt = 0; nt < 2; ++nt) acc[ft][nt] = (f32x4){0.f, 0.f, 0.f, 0.f};

    const int rr = tid >> 3;                // 0..31
    const int cc = (tid & 7) * 8;           // 0,8,..,56

    for (int k0 = 0; k0 < 256; k0 += 64) {
#pragma unroll
        for (int p = 0; p < 4; ++p) {
            const int row = rr + p * 32;
            int gx = node0 + row; if (gx >= n) gx = n - 1;
            *(bf16x8*)&Xs[row * LDR + cc] =
                *(const bf16x8*)&Xbf[(long long)gx * 256 + k0 + cc];
            *(bf16x8*)&Ws[row * LDR + cc] =
                *(const bf16x8*)&Wt[((long long)(fb * 128 + row)) * 256 + k0 + cc];
        }
        __syncthreads();
#pragma unroll
        for (int ks = 0; ks < 64; ks += 32) {
            bf16x8 bfrag[2];
#pragma unroll
            for (int nt = 0; nt < 2; ++nt)
                bfrag[nt] = *(const bf16x8*)&Xs[(wave * 32 + nt * 16 + col16) * LDR +
                                                ks + quad * 8];
#pragma unroll
            for (int ft = 0; ft < 8; ++ft) {
                const bf16x8 afrag =
                    *(const bf16x8*)&Ws[(ft * 16 + col16) * LDR + ks + quad * 8];
                acc[ft][0] = __builtin_amdgcn_mfma_f32_16x16x32_bf16(afrag, bfrag[0],
                                                                     acc[ft][0], 0, 0, 0);
                acc[ft][1] = __builtin_amdgcn_mfma_f32_16x16x32_bf16(afrag, bfrag[1],
                                                                     acc[ft][1], 0, 0, 0);
            }
        }
        __syncthreads();
    }

    // ---- epilogue: store h1 (bf16) + el/er ----
    float elp[2][2] = {{0.f, 0.f}, {0.f, 0.f}};   // [nt][head-in-block]
    float erp[2][2] = {{0.f, 0.f}, {0.f, 0.f}};
#pragma unroll
    for (int ft = 0; ft < 8; ++ft) {
        const int hb = ft >> 2;                    // head within block
        const int head = fb * 2 + hb;
        float alw[4], arw[4];
#pragma unroll
        for (int r = 0; r < 4; ++r) {
            const int d = (ft & 3) * 16 + quad * 4 + r;
            alw[r] = AL[head * 64 + d];
            arw[r] = AR[head * 64 + d];
        }
#pragma unroll
        for (int nt = 0; nt < 2; ++nt) {
            const int node = node0 + wave * 32 + nt * 16 + col16;
            if (node < n) {
                ushort4 pk;
                pk.x = f2bf(acc[ft][nt][0]); pk.y = f2bf(acc[ft][nt][1]);
                pk.z = f2bf(acc[ft][nt][2]); pk.w = f2bf(acc[ft][nt][3]);
                *(ushort4*)&Hout[(long long)node * 256 + fb * 128 + ft * 16 + quad * 4] = pk;
            }
#pragma unroll
            for (int r = 0; r < 4; ++r) {
                elp[nt][hb] = fmaf(acc[ft][nt][r], alw[r], elp[nt][hb]);
                erp[nt][hb] = fmaf(acc[ft][nt][r], arw[r], erp[nt][hb]);
            }
        }
    }
#pragma unroll
    for (int nt = 0; nt < 2; ++nt)
#pragma unroll
        for (int hb = 0; hb < 2; ++hb) {
            elp[nt][hb] += __shfl_xor(elp[nt][hb], 16, 64);
            elp[nt][hb] += __shfl_xor(elp[nt][hb], 32, 64);
            erp[nt][hb] += __shfl_xor(erp[nt][hb], 16, 64);
            erp[nt][hb] += __shfl_xor(erp[nt][hb], 32, 64);
        }
    if (quad == 0) {
#pragma unroll
        for (int nt = 0; nt < 2; ++nt) {
            const int node = node0 + wave * 32 + nt * 16 + col16;
            if (node < n) {
#pragma unroll
                for (int hb = 0; hb < 2; ++hb) {
                    el[node * 4 + fb * 2 + hb] = elp[nt][hb];
                    er[node * 4 + fb * 2 + hb] = erp[nt][hb];
                }
            }
        }
    }
}

// ---------------- fp32 register-tiled GEMM (layer 2) ----------------
template <int K, int M, int BN, int H, typename OT>
__global__ __launch_bounds__(256) void gemm_tile(const float* __restrict__ X,
                                                 const float* __restrict__ W,
                                                 const float* __restrict__ AL,
                                                 const float* __restrict__ AR,
                                                 OT* __restrict__ Hout,
                                                 float* __restrict__ el,
                                                 float* __restrict__ er, int n) {
    constexpr int BM = 64;
    constexpr int BK = 16;
    constexpr int BMP = BM + 4;
    constexpr int CT = BN / 16;
    constexpr int NHB = BN / 64;
    constexpr int WPH = 4 / NHB;
    __shared__ __align__(16) float As[BK * BMP];
    __shared__ __align__(16) float Bs[BK * BN];
    __shared__ float elp[4][BM];
    __shared__ float erp[4][BM];

    const int tid = threadIdx.x;
    const int tx = tid & 15;
    const int ty = tid >> 4;
    const int wave = tid >> 6;
    const int lane = tid & 63;
    const int row0 = blockIdx.x * BM;
    const int cb = blockIdx.y;

    float acc[4][CT];
#pragma unroll
    for (int i = 0; i < 4; ++i)
#pragma unroll
        for (int j = 0; j < CT; ++j) acc[i][j] = 0.f;

    const float4* X4 = (const float4*)X;
    const float4* W4 = (const float4*)W;

    for (int k0 = 0; k0 < K; k0 += BK) {
        {
            const int r = tid >> 2, c4 = tid & 3;
            const int row = row0 + r;
            float4 v = make_float4(0.f, 0.f, 0.f, 0.f);
            if (row < n) v = X4[(long long)row * (K / 4) + (k0 >> 2) + c4];
            As[(c4 * 4 + 0) * BMP + r] = v.x;
            As[(c4 * 4 + 1) * BMP + r] = v.y;
            As[(c4 * 4 + 2) * BMP + r] = v.z;
            As[(c4 * 4 + 3) * BMP + r] = v.w;
        }
        constexpr int BF4 = 4 * BN;
#pragma unroll
        for (int p = tid; p < BF4; p += 256) {
            const int r = p / (BN / 4), c4 = p % (BN / 4);
            ((float4*)Bs)[(r * BN + c4 * 4) >> 2] =
                W4[(((long long)(k0 + r)) * M + cb * BN + c4 * 4) >> 2];
        }
        __syncthreads();

#pragma unroll
        for (int kk = 0; kk < BK; ++kk) {
            const float4 av = *(const float4*)&As[kk * BMP + tx * 4];
            float bv[CT];
#pragma unroll
            for (int q = 0; q < CT / 4; ++q) {
                const float4 b = *(const float4*)&Bs[kk * BN + ty * CT + q * 4];
                bv[q * 4 + 0] = b.x; bv[q * 4 + 1] = b.y;
                bv[q * 4 + 2] = b.z; bv[q * 4 + 3] = b.w;
            }
            const float arow[4] = {av.x, av.y, av.z, av.w};
#pragma unroll
            for (int i = 0; i < 4; ++i)
#pragma unroll
                for (int j = 0; j < CT; ++j)
                    acc[i][j] = fmaf(arow[i], bv[j], acc[i][j]);
        }
        __syncthreads();
    }

    const int hq = ty / (16 / NHB);
    const int head = cb * NHB + hq;
    const int d0 = (ty % (16 / NHB)) * CT;
    float alw[CT], arw[CT];
#pragma unroll
    for (int j = 0; j < CT; ++j) {
        alw[j] = AL[head * 64 + d0 + j];
        arw[j] = AR[head * 64 + d0 + j];
    }

#pragma unroll
    for (int i = 0; i < 4; ++i) {
        const int row = row0 + tx * 4 + i;
        if (row < n) {
            const long long base = (long long)row * M + cb * BN + ty * CT;
            if (sizeof(OT) == 2) {
#pragma unroll
                for (int q = 0; q < CT / 4; ++q) {
                    ushort4 pk;
                    pk.x = f2bf(acc[i][q * 4 + 0]);
                    pk.y = f2bf(acc[i][q * 4 + 1]);
                    pk.z = f2bf(acc[i][q * 4 + 2]);
                    pk.w = f2bf(acc[i][q * 4 + 3]);
                    *(ushort4*)&((unsigned short*)Hout)[base + q * 4] = pk;
                }
            } else {
#pragma unroll
                for (int q = 0; q < CT / 4; ++q)
                    *(float4*)&((float*)Hout)[base + q * 4] =
                        make_float4(acc[i][q * 4], acc[i][q * 4 + 1],
                                    acc[i][q * 4 + 2], acc[i][q * 4 + 3]);
            }
        }
        float a = 0.f, b = 0.f;
#pragma unroll
        for (int j = 0; j < CT; ++j) {
            a = fmaf(acc[i][j], alw[j], a);
            b = fmaf(acc[i][j], arw[j], b);
        }
        a += __shfl_xor(a, 16, 64); a += __shfl_xor(a, 32, 64);
        b += __shfl_xor(b, 16, 64); b += __shfl_xor(b, 32, 64);
        if (lane < 16) {
            elp[wave][tx * 4 + i] = a;
            erp[wave][tx * 4 + i] = b;
        }
    }
    __syncthreads();
    for (int t = tid; t < BM * NHB; t += 256) {
        const int rl = t & 63, hb = t >> 6;
        const int row = row0 + rl;
        if (row < n) {
            float s = 0.f, s2 = 0.f;
#pragma unroll
            for (int w = 0; w < WPH; ++w) {
                s += elp[hb * WPH + w][rl];
                s2 += erp[hb * WPH + w][rl];
            }
            el[row * H + cb * NHB + hb] = s;
            er[row * H + cb * NHB + hb] = s2;
        }
    }
}

// ---------------- softmax gather-aggregate (no online-max) ----------------
template <int H, int D, int VEC, bool ELU, typename HT>
__global__ __launch_bounds__(256) void aggr_kernel(const HT* __restrict__ Hf,
                                                   const float* __restrict__ el,
                                                   const float* __restrict__ er,
                                                   const int* __restrict__ offs,
                                                   const int* __restrict__ csr_src,
                                                   const float* __restrict__ bias,
                                                   float* __restrict__ out, int n) {
    const int node = (blockIdx.x * blockDim.x + threadIdx.x) >> 6;
    const int lane = threadIdx.x & 63;
    if (node >= n) return;
    const int head = (lane * VEC) / D;
    const float erv = er[node * H + head];
    const int beg = offs[node], end = offs[node + 1];
    float l = 0.f;
    float acc[VEC];
#pragma unroll
    for (int j = 0; j < VEC; ++j) acc[j] = 0.f;
#pragma unroll 2
    for (int i = beg; i < end; ++i) {
        const int s = csr_src[i];
        float e = el[s * H + head] + erv;
        e = (e > 0.f) ? e : SLOPE * e;
        e = fminf(e, 80.f);
        const float p = __expf(e);
        const HT* hp = Hf + (long long)s * (H * D) + lane * VEC;
        float hv[VEC];
        if (sizeof(HT) == 2) {
            if (VEC == 4) {
                const ushort4 u = *(const ushort4*)hp;
                hv[0] = bf2f(u.x);
                if (VEC > 1) { hv[1] = bf2f(u.y); hv[2] = bf2f(u.z); hv[3] = bf2f(u.w); }
            } else {
                hv[0] = bf2f(*(const unsigned short*)hp);
            }
        } else {
            if (VEC == 4) {
                const float4 f = *(const float4*)hp;
                hv[0] = f.x;
                if (VEC > 1) { hv[1] = f.y; hv[2] = f.z; hv[3] = f.w; }
            } else {
                hv[0] = *(const float*)hp;
            }
        }
        l += p;
#pragma unroll
        for (int j = 0; j < VEC; ++j) acc[j] = fmaf(p, hv[j], acc[j]);
    }
    const float inv = (l > 0.f) ? 1.f / l : 0.f;
    float v[VEC];
#pragma unroll
    for (int j = 0; j < VEC; ++j) {
        v[j] = acc[j] * inv + bias[lane * VEC + j];
        if (ELU) v[j] = (v[j] > 0.f) ? v[j] : expm1f(v[j]);
    }
    float* op = out + (long long)node * (H * D) + lane * VEC;
    if (VEC == 4) {
        *(float4*)op = make_float4(v[0], v[1], v[2], v[3]);
    } else {
        *op = v[0];
    }
}

// ---------------- launch ----------------

extern "C" void kernel_launch(void* const* d_in, const int* in_sizes, int n_in,
                              void* d_out, int out_size, void* d_ws, size_t ws_size,
                              hipStream_t stream) {
    const float* feat = (const float*)d_in[0];
    const int*   src  = (const int*)d_in[1];
    const int*   dst  = (const int*)d_in[2];
    const float* W1   = (const float*)d_in[3];
    const float* al1  = (const float*)d_in[4];
    const float* ar1  = (const float*)d_in[5];
    const float* b1   = (const float*)d_in[6];
    const float* W2   = (const float*)d_in[7];
    const float* al2  = (const float*)d_in[8];
    const float* ar2  = (const float*)d_in[9];
    const float* b2   = (const float*)d_in[10];
    float* out = (float*)d_out;

    const int IN = 256, HID = 64, OUT = 64, H1 = 4, H2 = 1;
    const int N = in_sizes[0] / IN;   // 50000
    const int E = in_sizes[1];        // 800000

    size_t off = 0;
    auto alloc = [&](size_t bytes) {
        void* p = (char*)d_ws + off;
        off += (bytes + 255) & ~(size_t)255;
        return p;
    };
    int*   deg    = (int*)alloc((size_t)N * 4);
    int*   cursor = (int*)alloc((size_t)N * 4);
    int*   offs   = (int*)alloc((size_t)(N + 1) * 4);
    int*   csr    = (int*)alloc((size_t)E * 4);
    unsigned short* h1  = (unsigned short*)alloc((size_t)N * H1 * HID * 2);  // bf16
    unsigned short* xbf = (unsigned short*)alloc((size_t)N * IN * 2);        // bf16 X
    unsigned short* wt  = (unsigned short*)alloc((size_t)IN * H1 * HID * 2); // bf16 W1^T
    float* el1    = (float*)alloc((size_t)N * H1 * 4);
    float* er1    = (float*)alloc((size_t)N * H1 * 4);
    float* x2     = (float*)alloc((size_t)N * H1 * HID * 4);
    float* h2     = (float*)alloc((size_t)N * H2 * OUT * 4);
    float* el2    = (float*)alloc((size_t)N * H2 * 4);
    float* er2    = (float*)alloc((size_t)N * H2 * 4);
    (void)ws_size;

    hipMemsetAsync(deg, 0, (size_t)N * 4, stream);
    hipMemsetAsync(cursor, 0, (size_t)N * 4, stream);

    deg_kernel<<<(E + 255) / 256, 256, 0, stream>>>(dst, deg, E);
    scan_kernel<<<1, 1024, 0, stream>>>(deg, offs, N);
    fill_kernel<<<(E + 255) / 256, 256, 0, stream>>>(src, dst, offs, cursor, csr, E);

    // bf16 conversions for layer-1 MFMA
    {
        const int n4 = N * IN / 4;
        cvt_x_kernel<<<(n4 + 255) / 256, 256, 0, stream>>>((const float4*)feat,
                                                           (ushort4*)xbf, n4);
        cvt_wt_kernel<<<256, 256, 0, stream>>>(W1, wt);
    }

    // ---- layer 1 ----  (LDS-tiled MFMA: 128 nodes x 128 feats per block)
    {
        dim3 g((N + 127) / 128, 2);
        gemm1_mfma<<<g, 256, 0, stream>>>(xbf, wt, al1, ar1, h1, el1, er1, N);
    }
    aggr_kernel<4, 64, 4, true, unsigned short>
        <<<(N + 3) / 4, 256, 0, stream>>>(h1, el1, er1, offs, csr, b1, x2, N);
    // ---- layer 2 ----  (fp32 vector, BM=64, BN=64)
    {
        dim3 g((N + 63) / 64, 1);
        gemm_tile<256, 64, 64, 1, float>
            <<<g, 256, 0, stream>>>(x2, W2, al2, ar2, h2, el2, er2, N);
    }
    aggr_kernel<1, 64, 1, false, float>
        <<<(N + 3) / 4, 256, 0, stream>>>(h2, el2, er2, offs, csr, b2, out, N);
}

// Round 11
// 446.651 us; speedup vs baseline: 1.1498x; 1.0444x over previous
//
#include <hip/hip_runtime.h>
#include <hip/hip_bf16.h>
#include <math.h>

#define SLOPE 0.2f

typedef __attribute__((ext_vector_type(8))) short bf16x8;
typedef __attribute__((ext_vector_type(4))) float f32x4;

// bf16 helpers (manual, RNE)
__device__ inline unsigned short f2bf(float f) {
    unsigned u = __float_as_uint(f);
    u += 0x7FFF + ((u >> 16) & 1);
    return (unsigned short)(u >> 16);
}
__device__ inline float bf2f(unsigned short s) {
    return __uint_as_float(((unsigned)s) << 16);
}

// ---------------- CSR build ----------------

__global__ void deg_kernel(const int* __restrict__ dst, int* __restrict__ deg, int E) {
    int i = blockIdx.x * blockDim.x + threadIdx.x;
    if (i < E) atomicAdd(&deg[dst[i]], 1);
}

__global__ __launch_bounds__(1024) void scan_kernel(const int* __restrict__ deg,
                                                    int* __restrict__ offs, int n) {
    __shared__ int sums[1024];
    int t = threadIdx.x;
    int chunk = (n + 1023) >> 10;
    int beg = t * chunk;
    int end = beg + chunk; if (end > n) end = n;
    int s = 0;
    for (int i = beg; i < end && i >= 0; ++i) s += deg[i];
    sums[t] = s;
    __syncthreads();
    for (int off = 1; off < 1024; off <<= 1) {
        int v = (t >= off) ? sums[t - off] : 0;
        __syncthreads();
        sums[t] += v;
        __syncthreads();
    }
    int run = (t == 0) ? 0 : sums[t - 1];
    for (int i = beg; i < end; ++i) { offs[i] = run; run += deg[i]; }
    if (t == 1023) offs[n] = run;   // == E
}

__global__ void fill_kernel(const int* __restrict__ src, const int* __restrict__ dst,
                            const int* __restrict__ offs, int* __restrict__ cursor,
                            int* __restrict__ csr_src, int E) {
    int i = blockIdx.x * blockDim.x + threadIdx.x;
    if (i < E) {
        int d = dst[i];
        int p = atomicAdd(&cursor[d], 1);
        csr_src[offs[d] + p] = src[i];
    }
}

// ---------------- conversion kernels ----------------

__global__ void cvt_x_kernel(const float4* __restrict__ X4, ushort4* __restrict__ O4,
                             int n4) {
    int i = blockIdx.x * blockDim.x + threadIdx.x;
    if (i < n4) {
        const float4 v = X4[i];
        ushort4 o;
        o.x = f2bf(v.x); o.y = f2bf(v.y); o.z = f2bf(v.z); o.w = f2bf(v.w);
        O4[i] = o;
    }
}

// Wt[c][k] = bf16(W[k][c]); W is [K][M] with M columns. grid K blocks, M threads.
__global__ void cvt_wt_kernel(const float* __restrict__ W, unsigned short* __restrict__ Wt,
                              int K, int M) {
    const int k = blockIdx.x, c = threadIdx.x;
    Wt[c * K + k] = f2bf(W[k * M + c]);
}

// ---------------- layer-1 GEMM: LDS-tiled bf16 MFMA ----------------
// Block: 128 nodes x 128 feats (fb selects feature half), K=256 in 64-chunks.
// LDS rows padded to 72 ushorts -> 2-way bank aliasing (free, m136).
__global__ __launch_bounds__(256) void gemm1_mfma(const unsigned short* __restrict__ Xbf,
                                                  const unsigned short* __restrict__ Wt,
                                                  const float* __restrict__ AL,
                                                  const float* __restrict__ AR,
                                                  unsigned short* __restrict__ Hout,
                                                  float* __restrict__ el,
                                                  float* __restrict__ er, int n) {
    constexpr int LDR = 72;
    __shared__ __align__(16) unsigned short Xs[128 * LDR];
    __shared__ __align__(16) unsigned short Ws[128 * LDR];

    const int tid = threadIdx.x;
    const int wave = tid >> 6, lane = tid & 63;
    const int col16 = lane & 15, quad = lane >> 4;
    const int node0 = blockIdx.x * 128;
    const int fb = blockIdx.y;

    f32x4 acc[8][2];
#pragma unroll
    for (int ft = 0; ft < 8; ++ft)
#pragma unroll
        for (int nt = 0; nt < 2; ++nt) acc[ft][nt] = (f32x4){0.f, 0.f, 0.f, 0.f};

    const int rr = tid >> 3;
    const int cc = (tid & 7) * 8;

    for (int k0 = 0; k0 < 256; k0 += 64) {
#pragma unroll
        for (int p = 0; p < 4; ++p) {
            const int row = rr + p * 32;
            int gx = node0 + row; if (gx >= n) gx = n - 1;
            *(bf16x8*)&Xs[row * LDR + cc] =
                *(const bf16x8*)&Xbf[(long long)gx * 256 + k0 + cc];
            *(bf16x8*)&Ws[row * LDR + cc] =
                *(const bf16x8*)&Wt[((long long)(fb * 128 + row)) * 256 + k0 + cc];
        }
        __syncthreads();
#pragma unroll
        for (int ks = 0; ks < 64; ks += 32) {
            bf16x8 bfrag[2];
#pragma unroll
            for (int nt = 0; nt < 2; ++nt)
                bfrag[nt] = *(const bf16x8*)&Xs[(wave * 32 + nt * 16 + col16) * LDR +
                                                ks + quad * 8];
#pragma unroll
            for (int ft = 0; ft < 8; ++ft) {
                const bf16x8 afrag =
                    *(const bf16x8*)&Ws[(ft * 16 + col16) * LDR + ks + quad * 8];
                acc[ft][0] = __builtin_amdgcn_mfma_f32_16x16x32_bf16(afrag, bfrag[0],
                                                                     acc[ft][0], 0, 0, 0);
                acc[ft][1] = __builtin_amdgcn_mfma_f32_16x16x32_bf16(afrag, bfrag[1],
                                                                     acc[ft][1], 0, 0, 0);
            }
        }
        __syncthreads();
    }

    float elp[2][2] = {{0.f, 0.f}, {0.f, 0.f}};
    float erp[2][2] = {{0.f, 0.f}, {0.f, 0.f}};
#pragma unroll
    for (int ft = 0; ft < 8; ++ft) {
        const int hb = ft >> 2;
        const int head = fb * 2 + hb;
        float alw[4], arw[4];
#pragma unroll
        for (int r = 0; r < 4; ++r) {
            const int d = (ft & 3) * 16 + quad * 4 + r;
            alw[r] = AL[head * 64 + d];
            arw[r] = AR[head * 64 + d];
        }
#pragma unroll
        for (int nt = 0; nt < 2; ++nt) {
            const int node = node0 + wave * 32 + nt * 16 + col16;
            if (node < n) {
                ushort4 pk;
                pk.x = f2bf(acc[ft][nt][0]); pk.y = f2bf(acc[ft][nt][1]);
                pk.z = f2bf(acc[ft][nt][2]); pk.w = f2bf(acc[ft][nt][3]);
                *(ushort4*)&Hout[(long long)node * 256 + fb * 128 + ft * 16 + quad * 4] = pk;
            }
#pragma unroll
            for (int r = 0; r < 4; ++r) {
                elp[nt][hb] = fmaf(acc[ft][nt][r], alw[r], elp[nt][hb]);
                erp[nt][hb] = fmaf(acc[ft][nt][r], arw[r], erp[nt][hb]);
            }
        }
    }
#pragma unroll
    for (int nt = 0; nt < 2; ++nt)
#pragma unroll
        for (int hb = 0; hb < 2; ++hb) {
            elp[nt][hb] += __shfl_xor(elp[nt][hb], 16, 64);
            elp[nt][hb] += __shfl_xor(elp[nt][hb], 32, 64);
            erp[nt][hb] += __shfl_xor(erp[nt][hb], 16, 64);
            erp[nt][hb] += __shfl_xor(erp[nt][hb], 32, 64);
        }
    if (quad == 0) {
#pragma unroll
        for (int nt = 0; nt < 2; ++nt) {
            const int node = node0 + wave * 32 + nt * 16 + col16;
            if (node < n) {
#pragma unroll
                for (int hb = 0; hb < 2; ++hb) {
                    el[node * 4 + fb * 2 + hb] = elp[nt][hb];
                    er[node * 4 + fb * 2 + hb] = erp[nt][hb];
                }
            }
        }
    }
}

// ---------------- layer-2 GEMM: LDS-tiled bf16 MFMA (M=64) ----------------
// Block: 128 nodes x 64 feats; K=256 in 64-chunks. x2 input bf16, h2 out fp32.
__global__ __launch_bounds__(256) void gemm2_mfma(const unsigned short* __restrict__ Xbf,
                                                  const unsigned short* __restrict__ Wt,
                                                  const float* __restrict__ AL,
                                                  const float* __restrict__ AR,
                                                  float* __restrict__ Hout,
                                                  float* __restrict__ el,
                                                  float* __restrict__ er, int n) {
    constexpr int LDR = 72;
    __shared__ __align__(16) unsigned short Xs[128 * LDR];
    __shared__ __align__(16) unsigned short Ws[64 * LDR];

    const int tid = threadIdx.x;
    const int wave = tid >> 6, lane = tid & 63;
    const int col16 = lane & 15, quad = lane >> 4;
    const int node0 = blockIdx.x * 128;

    f32x4 acc[4][2];
#pragma unroll
    for (int ft = 0; ft < 4; ++ft)
#pragma unroll
        for (int nt = 0; nt < 2; ++nt) acc[ft][nt] = (f32x4){0.f, 0.f, 0.f, 0.f};

    const int rr = tid >> 3;
    const int cc = (tid & 7) * 8;

    for (int k0 = 0; k0 < 256; k0 += 64) {
#pragma unroll
        for (int p = 0; p < 4; ++p) {
            const int row = rr + p * 32;
            int gx = node0 + row; if (gx >= n) gx = n - 1;
            *(bf16x8*)&Xs[row * LDR + cc] =
                *(const bf16x8*)&Xbf[(long long)gx * 256 + k0 + cc];
        }
#pragma unroll
        for (int p = 0; p < 2; ++p) {
            const int row = rr + p * 32;
            *(bf16x8*)&Ws[row * LDR + cc] =
                *(const bf16x8*)&Wt[(long long)row * 256 + k0 + cc];
        }
        __syncthreads();
#pragma unroll
        for (int ks = 0; ks < 64; ks += 32) {
            bf16x8 bfrag[2];
#pragma unroll
            for (int nt = 0; nt < 2; ++nt)
                bfrag[nt] = *(const bf16x8*)&Xs[(wave * 32 + nt * 16 + col16) * LDR +
                                                ks + quad * 8];
#pragma unroll
            for (int ft = 0; ft < 4; ++ft) {
                const bf16x8 afrag =
                    *(const bf16x8*)&Ws[(ft * 16 + col16) * LDR + ks + quad * 8];
                acc[ft][0] = __builtin_amdgcn_mfma_f32_16x16x32_bf16(afrag, bfrag[0],
                                                                     acc[ft][0], 0, 0, 0);
                acc[ft][1] = __builtin_amdgcn_mfma_f32_16x16x32_bf16(afrag, bfrag[1],
                                                                     acc[ft][1], 0, 0, 0);
            }
        }
        __syncthreads();
    }

    float elp[2] = {0.f, 0.f}, erp[2] = {0.f, 0.f};
#pragma unroll
    for (int ft = 0; ft < 4; ++ft) {
        float alw[4], arw[4];
#pragma unroll
        for (int r = 0; r < 4; ++r) {
            const int d = ft * 16 + quad * 4 + r;
            alw[r] = AL[d];
            arw[r] = AR[d];
        }
#pragma unroll
        for (int nt = 0; nt < 2; ++nt) {
            const int node = node0 + wave * 32 + nt * 16 + col16;
            if (node < n) {
                *(float4*)&Hout[(long long)node * 64 + ft * 16 + quad * 4] =
                    make_float4(acc[ft][nt][0], acc[ft][nt][1],
                                acc[ft][nt][2], acc[ft][nt][3]);
            }
#pragma unroll
            for (int r = 0; r < 4; ++r) {
                elp[nt] = fmaf(acc[ft][nt][r], alw[r], elp[nt]);
                erp[nt] = fmaf(acc[ft][nt][r], arw[r], erp[nt]);
            }
        }
    }
#pragma unroll
    for (int nt = 0; nt < 2; ++nt) {
        elp[nt] += __shfl_xor(elp[nt], 16, 64);
        elp[nt] += __shfl_xor(elp[nt], 32, 64);
        erp[nt] += __shfl_xor(erp[nt], 16, 64);
        erp[nt] += __shfl_xor(erp[nt], 32, 64);
    }
    if (quad == 0) {
#pragma unroll
        for (int nt = 0; nt < 2; ++nt) {
            const int node = node0 + wave * 32 + nt * 16 + col16;
            if (node < n) {
                el[node] = elp[nt];
                er[node] = erp[nt];
            }
        }
    }
}

// ---------------- softmax gather-aggregate (shuffle-batched indices) ---------
// ONE WAVE PER NODE. Indices for 64 edges loaded coalesced (csr[base+lane]),
// broadcast per-edge via __shfl (uniform index -> scalar). Gathers for
// unrolled edges are independent -> stay in flight. No online-max (see R7).
template <int H, int D, int VEC, bool ELU, typename HT, typename OT>
__global__ __launch_bounds__(256) void aggr_kernel(const HT* __restrict__ Hf,
                                                   const float* __restrict__ el,
                                                   const float* __restrict__ er,
                                                   const int* __restrict__ offs,
                                                   const int* __restrict__ csr_src,
                                                   const float* __restrict__ bias,
                                                   OT* __restrict__ out, int n) {
    const int node = (blockIdx.x * blockDim.x + threadIdx.x) >> 6;
    const int lane = threadIdx.x & 63;
    if (node >= n) return;
    const int head = (lane * VEC) / D;
    const float erv = er[node * H + head];
    const int beg = offs[node], end = offs[node + 1];
    float l = 0.f;
    float acc[VEC];
#pragma unroll
    for (int j = 0; j < VEC; ++j) acc[j] = 0.f;

    for (int base = beg; base < end; base += 64) {
        const int cnt = (end - base < 64) ? (end - base) : 64;
        int myi = base + lane; if (myi >= end) myi = end - 1;
        const int sv = csr_src[myi];                  // coalesced batch load
#pragma unroll 4
        for (int j = 0; j < cnt; ++j) {
            const int s = __shfl(sv, j, 64);
            float e = el[s * H + head] + erv;
            e = (e > 0.f) ? e : SLOPE * e;
            e = fminf(e, 80.f);
            const float p = __expf(e);
            const HT* hp = Hf + (long long)s * (H * D) + lane * VEC;
            float hv[VEC];
            if (sizeof(HT) == 2) {
                if (VEC == 4) {
                    const ushort4 u = *(const ushort4*)hp;
                    hv[0] = bf2f(u.x);
                    if (VEC > 1) { hv[1] = bf2f(u.y); hv[2] = bf2f(u.z); hv[3] = bf2f(u.w); }
                } else {
                    hv[0] = bf2f(*(const unsigned short*)hp);
                }
            } else {
                if (VEC == 4) {
                    const float4 f = *(const float4*)hp;
                    hv[0] = f.x;
                    if (VEC > 1) { hv[1] = f.y; hv[2] = f.z; hv[3] = f.w; }
                } else {
                    hv[0] = *(const float*)hp;
                }
            }
            l += p;
#pragma unroll
            for (int q = 0; q < VEC; ++q) acc[q] = fmaf(p, hv[q], acc[q]);
        }
    }

    const float inv = (l > 0.f) ? 1.f / l : 0.f;
    float v[VEC];
#pragma unroll
    for (int j = 0; j < VEC; ++j) {
        v[j] = acc[j] * inv + bias[lane * VEC + j];
        if (ELU) v[j] = (v[j] > 0.f) ? v[j] : expm1f(v[j]);
    }
    if (sizeof(OT) == 2) {
        unsigned short* op = (unsigned short*)out + (long long)node * (H * D) + lane * VEC;
        if (VEC == 4) {
            ushort4 pk;
            pk.x = f2bf(v[0]); pk.y = f2bf(v[1]);
            pk.z = f2bf(v[2]); pk.w = f2bf(v[3]);
            *(ushort4*)op = pk;
        } else {
            *op = f2bf(v[0]);
        }
    } else {
        float* op = (float*)out + (long long)node * (H * D) + lane * VEC;
        if (VEC == 4) {
            *(float4*)op = make_float4(v[0], v[1], v[2], v[3]);
        } else {
            *op = v[0];
        }
    }
}

// ---------------- launch ----------------

extern "C" void kernel_launch(void* const* d_in, const int* in_sizes, int n_in,
                              void* d_out, int out_size, void* d_ws, size_t ws_size,
                              hipStream_t stream) {
    const float* feat = (const float*)d_in[0];
    const int*   src  = (const int*)d_in[1];
    const int*   dst  = (const int*)d_in[2];
    const float* W1   = (const float*)d_in[3];
    const float* al1  = (const float*)d_in[4];
    const float* ar1  = (const float*)d_in[5];
    const float* b1   = (const float*)d_in[6];
    const float* W2   = (const float*)d_in[7];
    const float* al2  = (const float*)d_in[8];
    const float* ar2  = (const float*)d_in[9];
    const float* b2   = (const float*)d_in[10];
    float* out = (float*)d_out;

    const int IN = 256, HID = 64, OUT = 64, H1 = 4, H2 = 1;
    const int N = in_sizes[0] / IN;   // 50000
    const int E = in_sizes[1];        // 800000

    size_t off = 0;
    auto alloc = [&](size_t bytes) {
        void* p = (char*)d_ws + off;
        off += (bytes + 255) & ~(size_t)255;
        return p;
    };
    int*   deg    = (int*)alloc((size_t)N * 4);
    int*   cursor = (int*)alloc((size_t)N * 4);
    int*   offs   = (int*)alloc((size_t)(N + 1) * 4);
    int*   csr    = (int*)alloc((size_t)E * 4);
    unsigned short* h1   = (unsigned short*)alloc((size_t)N * H1 * HID * 2); // bf16
    unsigned short* xbf  = (unsigned short*)alloc((size_t)N * IN * 2);       // bf16 X
    unsigned short* wt1  = (unsigned short*)alloc((size_t)IN * H1 * HID * 2);// bf16 W1^T
    unsigned short* wt2  = (unsigned short*)alloc((size_t)H1 * HID * H2 * OUT * 2); // W2^T
    unsigned short* x2bf = (unsigned short*)alloc((size_t)N * H1 * HID * 2); // bf16 x2
    float* el1    = (float*)alloc((size_t)N * H1 * 4);
    float* er1    = (float*)alloc((size_t)N * H1 * 4);
    float* h2     = (float*)alloc((size_t)N * H2 * OUT * 4);
    float* el2    = (float*)alloc((size_t)N * H2 * 4);
    float* er2    = (float*)alloc((size_t)N * H2 * 4);
    (void)ws_size;

    hipMemsetAsync(deg, 0, (size_t)N * 4, stream);
    hipMemsetAsync(cursor, 0, (size_t)N * 4, stream);

    deg_kernel<<<(E + 255) / 256, 256, 0, stream>>>(dst, deg, E);
    scan_kernel<<<1, 1024, 0, stream>>>(deg, offs, N);
    fill_kernel<<<(E + 255) / 256, 256, 0, stream>>>(src, dst, offs, cursor, csr, E);

    // bf16 conversions
    {
        const int n4 = N * IN / 4;
        cvt_x_kernel<<<(n4 + 255) / 256, 256, 0, stream>>>((const float4*)feat,
                                                           (ushort4*)xbf, n4);
        cvt_wt_kernel<<<256, 256, 0, stream>>>(W1, wt1, 256, 256);
        cvt_wt_kernel<<<256, 64, 0, stream>>>(W2, wt2, 256, 64);
    }

    // ---- layer 1 ----
    {
        dim3 g((N + 127) / 128, 2);
        gemm1_mfma<<<g, 256, 0, stream>>>(xbf, wt1, al1, ar1, h1, el1, er1, N);
    }
    aggr_kernel<4, 64, 4, true, unsigned short, unsigned short>
        <<<(N + 3) / 4, 256, 0, stream>>>(h1, el1, er1, offs, csr, b1, x2bf, N);
    // ---- layer 2 ----
    gemm2_mfma<<<(N + 127) / 128, 256, 0, stream>>>(x2bf, wt2, al2, ar2, h2, el2, er2, N);
    aggr_kernel<1, 64, 1, false, float, float>
        <<<(N + 3) / 4, 256, 0, stream>>>(h2, el2, er2, offs, csr, b2, out, N);
}